// Round 9
// baseline (340.349 us; speedup 1.0000x reference)
//
#include <hip/hip_runtime.h>
#include <hip/hip_bf16.h>

typedef unsigned short u16;
typedef float f32x4 __attribute__((ext_vector_type(4)));
typedef float f32x16 __attribute__((ext_vector_type(16)));
typedef __bf16 bf16x8 __attribute__((ext_vector_type(8)));
typedef u16 u16x4 __attribute__((ext_vector_type(4)));

#define NPIX 4096
#define CDIM 512
#define LOG2E 1.4426950408889634f

static __device__ __forceinline__ u16 f2bf(float f) {
  return __builtin_bit_cast(u16, (__bf16)f);
}
static __device__ __forceinline__ float bf2f(u16 u) {
  unsigned int v = ((unsigned int)u) << 16;
  return __builtin_bit_cast(float, v);
}
static __device__ __forceinline__ f32x16 zero16() {
  f32x16 z;
#pragma unroll
  for (int i = 0; i < 16; ++i) z[i] = 0.0f;
  return z;
}
static __device__ __forceinline__ f32x16 mfma16(bf16x8 a, bf16x8 b, f32x16 c) {
  return __builtin_amdgcn_mfma_f32_32x32x16_bf16(a, b, c, 0, 0, 0);
}

// ---------------------------------------------------------------------------
// Kernel 1: fused QKV projection (validated R1-R8, unchanged).
// ---------------------------------------------------------------------------
__global__ __launch_bounds__(640, 3) void proj_kernel(
    const float* __restrict__ x,
    const float* __restrict__ Wq, const float* __restrict__ bq,
    const float* __restrict__ Wk, const float* __restrict__ bk,
    const float* __restrict__ Wv, const float* __restrict__ bv,
    u16* __restrict__ qh, u16* __restrict__ ql,
    u16* __restrict__ kh, u16* __restrict__ vv)
{
  const int b = blockIdx.y;
  const int nbase = blockIdx.x * 64;
  const int tid = threadIdx.x;
  const int w = tid >> 6;
  const int lane = tid & 63;
  const int lhi = lane >> 5, llo = lane & 31;

  __shared__ float xs[2048];  // [32 k][64 n] fp32, 8 KB

  const float* xb = x + (size_t)b * CDIM * NPIX + nbase;

  const float* wrow[2];
#pragma unroll
  for (int rb = 0; rb < 2; ++rb) {
    int row = 64 * w + 32 * rb + llo;
    wrow[rb] = (row < 64) ? (Wq + (size_t)row * CDIM)
             : (row < 128) ? (Wk + (size_t)(row - 64) * CDIM)
                           : (Wv + (size_t)(row - 128) * CDIM);
  }

  f32x16 acc[2][2];
  acc[0][0] = zero16(); acc[0][1] = zero16();
  acc[1][0] = zero16(); acc[1][1] = zero16();

  for (int ks2 = 0; ks2 < 16; ++ks2) {
    __syncthreads();
    if (tid < 512) {
      int r = tid >> 4, ci = (tid & 15) << 2;
      *(f32x4*)&xs[r * 64 + ci] =
          *(const f32x4*)&xb[(size_t)(ks2 * 32 + r) * NPIX + ci];
    }
    __syncthreads();

#pragma unroll
    for (int kk = 0; kk < 2; ++kk) {
      const int ksoff = ks2 * 32 + kk * 16;
      bf16x8 af[2];
#pragma unroll
      for (int rb = 0; rb < 2; ++rb) {
        const float* wp = wrow[rb] + ksoff + 8 * lhi;
        f32x4 w0 = *(const f32x4*)(wp);
        f32x4 w1 = *(const f32x4*)(wp + 4);
#pragma unroll
        for (int j = 0; j < 4; ++j) { af[rb][j] = (__bf16)w0[j]; af[rb][4 + j] = (__bf16)w1[j]; }
      }
      bf16x8 bfr[2];
#pragma unroll
      for (int cb = 0; cb < 2; ++cb) {
        int n = 32 * cb + llo;
#pragma unroll
        for (int j = 0; j < 8; ++j)
          bfr[cb][j] = (__bf16)xs[(kk * 16 + 8 * lhi + j) * 64 + n];
      }
#pragma unroll
      for (int rb = 0; rb < 2; ++rb)
#pragma unroll
        for (int cb = 0; cb < 2; ++cb)
          acc[rb][cb] = mfma16(af[rb], bfr[cb], acc[rb][cb]);
    }
  }

  // Epilogue: C/D layout col = lane&31 (n), row = (r&3)+8*(r>>2)+4*lhi.
#pragma unroll
  for (int rb = 0; rb < 2; ++rb) {
#pragma unroll
    for (int cb = 0; cb < 2; ++cb) {
      int n = nbase + 32 * cb + llo;
#pragma unroll
      for (int gq = 0; gq < 4; ++gq) {
        int dr0 = 8 * gq + 4 * lhi;
        float vals[4];
#pragma unroll
        for (int jj = 0; jj < 4; ++jj) {
          int Mrow = 64 * w + 32 * rb + dr0 + jj;
          float bias = (Mrow < 64) ? bq[Mrow] : (Mrow < 128) ? bk[Mrow - 64] : bv[Mrow - 128];
          vals[jj] = acc[rb][cb][4 * gq + jj] + bias;
        }
        if (w == 0) {  // q: hi/lo pair, pre-scaled by log2(e)
          u16x4 hi, lo;
#pragma unroll
          for (int jj = 0; jj < 4; ++jj) {
            float vq = vals[jj] * LOG2E;
            hi[jj] = f2bf(vq);
            lo[jj] = f2bf(vq - bf2f(hi[jj]));
          }
          int o = 32 * rb + dr0;
          size_t off = ((size_t)b * NPIX + n) * 64 + o;
          *(u16x4*)(qh + off) = hi;
          *(u16x4*)(ql + off) = lo;
        } else if (w == 1) {  // k: hi only
          u16x4 hi;
#pragma unroll
          for (int jj = 0; jj < 4; ++jj) hi[jj] = f2bf(vals[jj]);
          int o = 32 * rb + dr0;
          size_t off = ((size_t)b * NPIX + n) * 64 + o;
          *(u16x4*)(kh + off) = hi;
        } else {
#pragma unroll
          for (int jj = 0; jj < 4; ++jj) {
            int c = 64 * w - 128 + 32 * rb + dr0 + jj;
            vv[((size_t)b * CDIM + c) * NPIX + n] = f2bf(vals[jj]);
          }
        }
      }
    }
  }
}

// ---------------------------------------------------------------------------
// Kernel 2: single-pass attention, 16 waves / 4 per SIMD (R7/R8 dataflow).
// Allocator history: bare lb(1024) -> 64 VGPR (spills); lb(1024,4) -> STILL
// 64 VGPR (the 2nd arg only caps at 512/min, doesn't stop the heuristic
// from targeting 8 waves/EU). Fix: amdgpu_waves_per_eu(4,4) — an explicit
// MAX tells the backend to target exactly 4 waves/EU and allocate up to
// 128 VGPRs (demand ~120). Verification signal: VGPR_Count ~128, FETCH
// 487->~45MB, WRITE 259->~33MB.
// ---------------------------------------------------------------------------

#define LOADK(T) do {                                                         \
  size_t koff_ = kbl + (size_t)(T) * (256 * 64);                              \
  _Pragma("unroll") for (int s_ = 0; s_ < 4; ++s_)                            \
    kf[s_] = *(const bf16x8*)(kh + koff_ + 16 * s_);                          \
} while (0)

#define S_PHASE(BUFB) do {                                                    \
  f32x16 sacc_ = zero16();                                                    \
  _Pragma("unroll") for (int s_ = 0; s_ < 4; ++s_)                            \
    sacc_ = mfma16(qfh[s_], kf[s_], sacc_);                                   \
  _Pragma("unroll") for (int s_ = 0; s_ < 4; ++s_)                            \
    sacc_ = mfma16(qfl[s_], kf[s_], sacc_);                                   \
  _Pragma("unroll") for (int r_ = 0; r_ < 16; ++r_) {                         \
    float p_ = __builtin_amdgcn_exp2f(sacc_[r_]);                             \
    u16 pb_ = f2bf(p_);                                                       \
    l_part[r_] += bf2f(pb_);                                                  \
    int row_ = 32 * rb_s + (r_ & 3) + 8 * (r_ >> 2) + 4 * lhi;                \
    int byt_ = (row_ * 512 + (32 * kb + llo) * 2) ^ ((row_ & 15) << 4);       \
    *(u16*)((BUFB) + byt_) = pb_;                                             \
  }                                                                           \
} while (0)

#define PV_PHASE(BUFB, T) do {                                                \
  _Pragma("unroll") for (int s_ = 0; s_ < 16; ++s_) {                         \
    int ko_ = (16 * s_ + 8 * lhi) * 2;                                        \
    int by0_ = (llo * 512 + ko_) ^ ((llo & 15) << 4);                         \
    int by1_ = ((32 + llo) * 512 + ko_) ^ ((llo & 15) << 4);                  \
    bf16x8 pa0_ = *(const bf16x8*)((BUFB) + by0_);                            \
    bf16x8 pa1_ = *(const bf16x8*)((BUFB) + by1_);                            \
    bf16x8 vf_ = *(const bf16x8*)(vv + vbase + (size_t)(T) * 256 + 16 * s_);  \
    acc0 = mfma16(pa0_, vf_, acc0);                                           \
    acc1 = mfma16(pa1_, vf_, acc1);                                           \
  }                                                                           \
} while (0)

__global__ __launch_bounds__(1024)
__attribute__((amdgpu_waves_per_eu(4, 4)))
void attn_kernel(
    const u16* __restrict__ qh, const u16* __restrict__ ql,
    const u16* __restrict__ kh, const u16* __restrict__ vv,
    const float* __restrict__ x, const float* __restrict__ gamma,
    float* __restrict__ out)
{
  const int bid = blockIdx.x;
  const int sw = ((bid & 7) << 5) | (bid >> 3);  // bijective, 256 = 8*32
  const int batch = sw >> 6;
  const int qbase = (sw & 63) * 64;
  const int tid = threadIdx.x;
  const int w = tid >> 6;        // 16 waves
  const int lane = tid & 63;
  const int lhi = lane >> 5, llo = lane & 31;
  const int rb_s = w & 1;        // S row half
  const int kb = w >> 1;         // this wave's 32-key block (0..7)

  __shared__ alignas(16) char Psm[65536];  // 2 x [64 q][256 k] bf16, swizzled
  char* Pb0 = Psm;
  char* Pb1 = Psm + 32768;
  // Reductions alias Pb0 (last read of Pb0 is PV in iter 15, pre-barrier).
  float* lred = (float*)Psm;              // [64][8]
  float* rl_lds = (float*)(Psm + 2048);   // [64]

  bf16x8 qfh[4], qfl[4];
  {
    size_t qoff = ((size_t)batch * NPIX + qbase + 32 * rb_s + llo) * 64 + 8 * lhi;
#pragma unroll
    for (int s = 0; s < 4; ++s) {
      qfh[s] = *(const bf16x8*)(qh + qoff + 16 * s);
      qfl[s] = *(const bf16x8*)(ql + qoff + 16 * s);
    }
  }

  const size_t kbl = ((size_t)batch * NPIX + 32 * kb + llo) * 64 + 8 * lhi;
  const size_t vbase = ((size_t)batch * CDIM + 32 * w + llo) * NPIX + 8 * lhi;

  f32x16 acc0 = zero16(), acc1 = zero16();
  float l_part[16];
#pragma unroll
  for (int r = 0; r < 16; ++r) l_part[r] = 0.0f;

  bf16x8 kf[4];  // single K fragment set, issue-early (R4/R6-proven)

  // Prologue: K(0) -> kf, S(0) -> Pb0.
  LOADK(0);
  S_PHASE(Pb0);
  __syncthreads();

  // Main loop: iter t does PV of tile t-1 and S of tile t; 1 barrier/iter.
  for (int tt = 0; tt < 7; ++tt) {
    const int t0 = 2 * tt + 1;  // odd
    LOADK(t0);
    PV_PHASE(Pb0, t0 - 1);
    S_PHASE(Pb1);
    __syncthreads();
    const int t1 = t0 + 1;      // even
    LOADK(t1);
    PV_PHASE(Pb1, t1 - 1);
    S_PHASE(Pb0);
    __syncthreads();
  }
  // t = 15:
  LOADK(15);
  PV_PHASE(Pb0, 14);
  S_PHASE(Pb1);
  __syncthreads();
  PV_PHASE(Pb1, 15);

  // Denominator: reduce l_part over the 32 key-lanes, merge the 8 key-block
  // waves per row-half in LDS (aliased onto Pb0).
#pragma unroll
  for (int d = 1; d < 32; d <<= 1)
#pragma unroll
    for (int r = 0; r < 16; ++r) l_part[r] += __shfl_xor(l_part[r], d, 64);
  if (llo == 0) {
#pragma unroll
    for (int r = 0; r < 16; ++r) {
      int row = 32 * rb_s + (r & 3) + 8 * (r >> 2) + 4 * lhi;
      lred[row * 8 + kb] = l_part[r];
    }
  }
  __syncthreads();
  if (tid < 64) {
    float s = 0.0f;
#pragma unroll
    for (int j = 0; j < 8; ++j) s += lred[tid * 8 + j];
    rl_lds[tid] = 1.0f / s;
  }
  __syncthreads();

  const float g = gamma[0];
  const int c = 32 * w + llo;
#pragma unroll
  for (int ab = 0; ab < 2; ++ab) {
    const f32x16& a = ab ? acc1 : acc0;
#pragma unroll
    for (int gq = 0; gq < 4; ++gq) {
      int qrow = 32 * ab + 8 * gq + 4 * lhi;
      size_t off = ((size_t)batch * CDIM + c) * NPIX + qbase + qrow;
      f32x4 xv = *(const f32x4*)(x + off);
      f32x4 rlv = *(const f32x4*)&rl_lds[qrow];
      f32x4 ov;
#pragma unroll
      for (int jj = 0; jj < 4; ++jj)
        ov[jj] = g * a[4 * gq + jj] * rlv[jj] + xv[jj];
      *(f32x4*)(out + off) = ov;
    }
  }
}

extern "C" void kernel_launch(void* const* d_in, const int* in_sizes, int n_in,
                              void* d_out, int out_size, void* d_ws, size_t ws_size,
                              hipStream_t stream) {
  (void)in_sizes; (void)n_in; (void)out_size; (void)ws_size;
  const float* x     = (const float*)d_in[0];
  const float* Wq    = (const float*)d_in[1];
  const float* bq    = (const float*)d_in[2];
  const float* Wk    = (const float*)d_in[3];
  const float* bk    = (const float*)d_in[4];
  const float* Wv    = (const float*)d_in[5];
  const float* bv    = (const float*)d_in[6];
  const float* gamma = (const float*)d_in[7];
  float* out = (float*)d_out;

  // Workspace layout (bytes): qh 0..2M, ql 2..4M, kh 4..6M, v 6..22M.
  char* ws = (char*)d_ws;
  u16* qh = (u16*)(ws);
  u16* ql = (u16*)(ws + (2u << 20));
  u16* kh = (u16*)(ws + (4u << 20));
  u16* vv = (u16*)(ws + (6u << 20));

  proj_kernel<<<dim3(64, 4), 640, 0, stream>>>(x, Wq, bq, Wk, bk, Wv, bv,
                                               qh, ql, kh, vv);
  attn_kernel<<<256, 1024, 0, stream>>>(qh, ql, kh, vv, x, gamma, out);
}

// Round 10
// 308.284 us; speedup vs baseline: 1.1040x; 1.1040x over previous
//
#include <hip/hip_runtime.h>
#include <hip/hip_bf16.h>

typedef unsigned short u16;
typedef float f32x4 __attribute__((ext_vector_type(4)));
typedef float f32x16 __attribute__((ext_vector_type(16)));
typedef __bf16 bf16x8 __attribute__((ext_vector_type(8)));
typedef u16 u16x4 __attribute__((ext_vector_type(4)));

#define NPIX 4096
#define CDIM 512
#define LOG2E 1.4426950408889634f

static __device__ __forceinline__ u16 f2bf(float f) {
  return __builtin_bit_cast(u16, (__bf16)f);
}
static __device__ __forceinline__ float bf2f(u16 u) {
  unsigned int v = ((unsigned int)u) << 16;
  return __builtin_bit_cast(float, v);
}
static __device__ __forceinline__ f32x16 zero16() {
  f32x16 z;
#pragma unroll
  for (int i = 0; i < 16; ++i) z[i] = 0.0f;
  return z;
}
static __device__ __forceinline__ f32x16 mfma16(bf16x8 a, bf16x8 b, f32x16 c) {
  return __builtin_amdgcn_mfma_f32_32x32x16_bf16(a, b, c, 0, 0, 0);
}

// ---------------------------------------------------------------------------
// Kernel 1: fused QKV projection (validated R1-R9, unchanged).
// ---------------------------------------------------------------------------
__global__ __launch_bounds__(640, 3) void proj_kernel(
    const float* __restrict__ x,
    const float* __restrict__ Wq, const float* __restrict__ bq,
    const float* __restrict__ Wk, const float* __restrict__ bk,
    const float* __restrict__ Wv, const float* __restrict__ bv,
    u16* __restrict__ qh, u16* __restrict__ ql,
    u16* __restrict__ kh, u16* __restrict__ vv)
{
  const int b = blockIdx.y;
  const int nbase = blockIdx.x * 64;
  const int tid = threadIdx.x;
  const int w = tid >> 6;
  const int lane = tid & 63;
  const int lhi = lane >> 5, llo = lane & 31;

  __shared__ float xs[2048];  // [32 k][64 n] fp32, 8 KB

  const float* xb = x + (size_t)b * CDIM * NPIX + nbase;

  const float* wrow[2];
#pragma unroll
  for (int rb = 0; rb < 2; ++rb) {
    int row = 64 * w + 32 * rb + llo;
    wrow[rb] = (row < 64) ? (Wq + (size_t)row * CDIM)
             : (row < 128) ? (Wk + (size_t)(row - 64) * CDIM)
                           : (Wv + (size_t)(row - 128) * CDIM);
  }

  f32x16 acc[2][2];
  acc[0][0] = zero16(); acc[0][1] = zero16();
  acc[1][0] = zero16(); acc[1][1] = zero16();

  for (int ks2 = 0; ks2 < 16; ++ks2) {
    __syncthreads();
    if (tid < 512) {
      int r = tid >> 4, ci = (tid & 15) << 2;
      *(f32x4*)&xs[r * 64 + ci] =
          *(const f32x4*)&xb[(size_t)(ks2 * 32 + r) * NPIX + ci];
    }
    __syncthreads();

#pragma unroll
    for (int kk = 0; kk < 2; ++kk) {
      const int ksoff = ks2 * 32 + kk * 16;
      bf16x8 af[2];
#pragma unroll
      for (int rb = 0; rb < 2; ++rb) {
        const float* wp = wrow[rb] + ksoff + 8 * lhi;
        f32x4 w0 = *(const f32x4*)(wp);
        f32x4 w1 = *(const f32x4*)(wp + 4);
#pragma unroll
        for (int j = 0; j < 4; ++j) { af[rb][j] = (__bf16)w0[j]; af[rb][4 + j] = (__bf16)w1[j]; }
      }
      bf16x8 bfr[2];
#pragma unroll
      for (int cb = 0; cb < 2; ++cb) {
        int n = 32 * cb + llo;
#pragma unroll
        for (int j = 0; j < 8; ++j)
          bfr[cb][j] = (__bf16)xs[(kk * 16 + 8 * lhi + j) * 64 + n];
      }
#pragma unroll
      for (int rb = 0; rb < 2; ++rb)
#pragma unroll
        for (int cb = 0; cb < 2; ++cb)
          acc[rb][cb] = mfma16(af[rb], bfr[cb], acc[rb][cb]);
    }
  }

  // Epilogue: C/D layout col = lane&31 (n), row = (r&3)+8*(r>>2)+4*lhi.
#pragma unroll
  for (int rb = 0; rb < 2; ++rb) {
#pragma unroll
    for (int cb = 0; cb < 2; ++cb) {
      int n = nbase + 32 * cb + llo;
#pragma unroll
      for (int gq = 0; gq < 4; ++gq) {
        int dr0 = 8 * gq + 4 * lhi;
        float vals[4];
#pragma unroll
        for (int jj = 0; jj < 4; ++jj) {
          int Mrow = 64 * w + 32 * rb + dr0 + jj;
          float bias = (Mrow < 64) ? bq[Mrow] : (Mrow < 128) ? bk[Mrow - 64] : bv[Mrow - 128];
          vals[jj] = acc[rb][cb][4 * gq + jj] + bias;
        }
        if (w == 0) {  // q: hi/lo pair, pre-scaled by log2(e)
          u16x4 hi, lo;
#pragma unroll
          for (int jj = 0; jj < 4; ++jj) {
            float vq = vals[jj] * LOG2E;
            hi[jj] = f2bf(vq);
            lo[jj] = f2bf(vq - bf2f(hi[jj]));
          }
          int o = 32 * rb + dr0;
          size_t off = ((size_t)b * NPIX + n) * 64 + o;
          *(u16x4*)(qh + off) = hi;
          *(u16x4*)(ql + off) = lo;
        } else if (w == 1) {  // k: hi only
          u16x4 hi;
#pragma unroll
          for (int jj = 0; jj < 4; ++jj) hi[jj] = f2bf(vals[jj]);
          int o = 32 * rb + dr0;
          size_t off = ((size_t)b * NPIX + n) * 64 + o;
          *(u16x4*)(kh + off) = hi;
        } else {
#pragma unroll
          for (int jj = 0; jj < 4; ++jj) {
            int c = 64 * w - 128 + 32 * rb + dr0 + jj;
            vv[((size_t)b * CDIM + c) * NPIX + n] = f2bf(vals[jj]);
          }
        }
      }
    }
  }
}

// ---------------------------------------------------------------------------
// Kernel 2: single-pass attention, 2 blocks/CU via small LDS.
// Residency law measured R2-R9: LDS co-residency budget is ~64 KB/CU
// (34.3KB blocks never co-scheduled: 2x34.3 > 64). 1024-thr blocks get
// VGPR pinned to 64 (3 failed knob rounds). So: 512-thr blocks (natural
// VGPR 96-128, R2/R4/R6-measured) + LDS 17.7 KB -> 2 blocks/CU = 4
// waves/SIMD TLP. Channel-split grid 512 = 64qt x 4batch x 2chhalf
// (R4-validated mapping); 128-key tiles, SINGLE P buffer [64][128] bf16
// (16 KB, R4's 0-conflict swizzle), 2 barriers/iter — cross-block TLP
// fills barrier gaps. Per-wave state == R4's measured-96-VGPR shape.
// ---------------------------------------------------------------------------

#define LOADK(T) do {                                                         \
  size_t koff_ = kbl + (size_t)(T) * (128 * 64);                              \
  _Pragma("unroll") for (int s_ = 0; s_ < 4; ++s_)                            \
    kf[s_] = *(const bf16x8*)(kh + koff_ + 16 * s_);                          \
} while (0)

#define S_PHASE() do {                                                        \
  f32x16 sacc_ = zero16();                                                    \
  _Pragma("unroll") for (int s_ = 0; s_ < 4; ++s_)                            \
    sacc_ = mfma16(qfh[s_], kf[s_], sacc_);                                   \
  _Pragma("unroll") for (int s_ = 0; s_ < 4; ++s_)                            \
    sacc_ = mfma16(qfl[s_], kf[s_], sacc_);                                   \
  _Pragma("unroll") for (int r_ = 0; r_ < 16; ++r_) {                         \
    float p_ = __builtin_amdgcn_exp2f(sacc_[r_]);                             \
    u16 pb_ = f2bf(p_);                                                       \
    l_part[r_] += bf2f(pb_);                                                  \
    int row_ = 32 * rb_s + (r_ & 3) + 8 * (r_ >> 2) + 4 * lhi;                \
    int byt_ = (row_ * 256 + (32 * kq + llo) * 2) ^ ((row_ & 15) << 4);       \
    *(u16*)(Pb + byt_) = pb_;                                                 \
  }                                                                           \
} while (0)

#define PV_PHASE(T) do {                                                      \
  _Pragma("unroll") for (int s_ = 0; s_ < 8; ++s_) {                          \
    int ko_ = (16 * s_ + 8 * lhi) * 2;                                        \
    int by0_ = (llo * 256 + ko_) ^ ((llo & 15) << 4);                         \
    int by1_ = ((32 + llo) * 256 + ko_) ^ ((llo & 15) << 4);                  \
    bf16x8 pa0_ = *(const bf16x8*)(Pb + by0_);                                \
    bf16x8 pa1_ = *(const bf16x8*)(Pb + by1_);                                \
    bf16x8 vf_ = *(const bf16x8*)(vv + vbase + (size_t)(T) * 128 + 16 * s_);  \
    acc0 = mfma16(pa0_, vf_, acc0);                                           \
    acc1 = mfma16(pa1_, vf_, acc1);                                           \
  }                                                                           \
} while (0)

__global__ __launch_bounds__(512, 2) void attn_kernel(
    const u16* __restrict__ qh, const u16* __restrict__ ql,
    const u16* __restrict__ kh, const u16* __restrict__ vv,
    const float* __restrict__ x, const float* __restrict__ gamma,
    float* __restrict__ out)
{
  const int bid = blockIdx.x;
  const int sw = ((bid & 7) << 6) | (bid >> 3);  // bijective, 512 = 8*64
  const int batch = sw >> 7;          // XCD pair {2b,2b+1} -> batch b
  const int chhalf = (sw >> 6) & 1;   // XCD 2b+c -> channel half c
  const int qbase = (sw & 63) * 64;
  const int tid = threadIdx.x;
  const int w = tid >> 6;
  const int lane = tid & 63;
  const int lhi = lane >> 5, llo = lane & 31;
  const int rb_s = w & 1;   // S row half
  const int kq = w >> 1;    // S key block (0..3) within the 128-key tile

  __shared__ alignas(16) char Pb[16384];  // [64 q][128 k] bf16, swizzled
  __shared__ float lred[64][4];
  __shared__ alignas(16) float rl_lds[64];

  bf16x8 qfh[4], qfl[4];
  {
    size_t qoff = ((size_t)batch * NPIX + qbase + 32 * rb_s + llo) * 64 + 8 * lhi;
#pragma unroll
    for (int s = 0; s < 4; ++s) {
      qfh[s] = *(const bf16x8*)(qh + qoff + 16 * s);
      qfl[s] = *(const bf16x8*)(ql + qoff + 16 * s);
    }
  }

  const size_t kbl = ((size_t)batch * NPIX + 32 * kq + llo) * 64 + 8 * lhi;
  const size_t vbase =
      ((size_t)batch * CDIM + chhalf * 256 + 32 * w + llo) * NPIX + 8 * lhi;

  f32x16 acc0 = zero16(), acc1 = zero16();
  float l_part[16];
#pragma unroll
  for (int r = 0; r < 16; ++r) l_part[r] = 0.0f;

  bf16x8 kf[4];  // single K fragment set, issue-early

  // Prologue: K(0) -> kf, S(0) -> Pb.
  LOADK(0);
  S_PHASE();
  __syncthreads();

  // Iter t: issue K(t+1), PV over P[t] (+V tile t), barrier, S writes P[t+1].
  for (int t = 0; t < 31; ++t) {
    LOADK(t + 1);
    PV_PHASE(t);
    __syncthreads();
    S_PHASE();
    __syncthreads();
  }
  PV_PHASE(31);

  // Denominator: reduce l_part over 32 key-lanes, merge 4 key-blocks in LDS.
#pragma unroll
  for (int d = 1; d < 32; d <<= 1)
#pragma unroll
    for (int r = 0; r < 16; ++r) l_part[r] += __shfl_xor(l_part[r], d, 64);
  if (llo == 0) {
#pragma unroll
    for (int r = 0; r < 16; ++r) {
      int row = 32 * rb_s + (r & 3) + 8 * (r >> 2) + 4 * lhi;
      lred[row][kq] = l_part[r];
    }
  }
  __syncthreads();
  if (tid < 64)
    rl_lds[tid] = 1.0f / (lred[tid][0] + lred[tid][1] + lred[tid][2] + lred[tid][3]);
  __syncthreads();

  const float g = gamma[0];
  const int c = chhalf * 256 + 32 * w + llo;
#pragma unroll
  for (int ab = 0; ab < 2; ++ab) {
    const f32x16& a = ab ? acc1 : acc0;
#pragma unroll
    for (int gq = 0; gq < 4; ++gq) {
      int qrow = 32 * ab + 8 * gq + 4 * lhi;
      size_t off = ((size_t)batch * CDIM + c) * NPIX + qbase + qrow;
      f32x4 xv = *(const f32x4*)(x + off);
      f32x4 rlv = *(const f32x4*)&rl_lds[qrow];
      f32x4 ov;
#pragma unroll
      for (int jj = 0; jj < 4; ++jj)
        ov[jj] = g * a[4 * gq + jj] * rlv[jj] + xv[jj];
      *(f32x4*)(out + off) = ov;
    }
  }
}

extern "C" void kernel_launch(void* const* d_in, const int* in_sizes, int n_in,
                              void* d_out, int out_size, void* d_ws, size_t ws_size,
                              hipStream_t stream) {
  (void)in_sizes; (void)n_in; (void)out_size; (void)ws_size;
  const float* x     = (const float*)d_in[0];
  const float* Wq    = (const float*)d_in[1];
  const float* bq    = (const float*)d_in[2];
  const float* Wk    = (const float*)d_in[3];
  const float* bk    = (const float*)d_in[4];
  const float* Wv    = (const float*)d_in[5];
  const float* bv    = (const float*)d_in[6];
  const float* gamma = (const float*)d_in[7];
  float* out = (float*)d_out;

  // Workspace layout (bytes): qh 0..2M, ql 2..4M, kh 4..6M, v 6..22M.
  char* ws = (char*)d_ws;
  u16* qh = (u16*)(ws);
  u16* ql = (u16*)(ws + (2u << 20));
  u16* kh = (u16*)(ws + (4u << 20));
  u16* vv = (u16*)(ws + (6u << 20));

  proj_kernel<<<dim3(64, 4), 640, 0, stream>>>(x, Wq, bq, Wk, bk, Wv, bv,
                                               qh, ql, kh, vv);
  attn_kernel<<<512, 512, 0, stream>>>(qh, ql, kh, vv, x, gamma, out);
}